// Round 7
// baseline (277.016 us; speedup 1.0000x reference)
//
#include <hip/hip_runtime.h>
#include <stdint.h>

#define DIM  1024
#define NSRC 4096
#define NTGT 4096

typedef __bf16 bf16_t;
typedef bf16_t bf16x8 __attribute__((ext_vector_type(8)));
typedef float  fx4    __attribute__((ext_vector_type(4)));

static __device__ __forceinline__ unsigned short f2bf(float f) {
  union { float f; uint32_t u; } v; v.f = f;
  return (unsigned short)((v.u + 0x7FFFu + ((v.u >> 16) & 1u)) >> 16);
}
static __device__ __forceinline__ float bf2f(unsigned short h) {
  union { uint32_t u; float f; } v; v.u = ((uint32_t)h) << 16;
  return v.f;
}

// async global->LDS, 16B per lane; lds dest is wave-uniform base + lane*16
static __device__ __forceinline__ void gl_lds16(const unsigned short* g, unsigned short* l) {
  __builtin_amdgcn_global_load_lds(
      (__attribute__((address_space(1))) const void*)g,
      (__attribute__((address_space(3))) void*)l, 16, 0, 0);
}

typedef const __attribute__((address_space(3))) unsigned short* lds3p;

// inline-asm ds_read_b128 with compile-time byte offset immediate.
template <int IMM>
static __device__ __forceinline__ bf16x8 dsr128(lds3p p) {
  bf16x8 r;
  asm volatile("ds_read_b128 %0, %1 offset:%2" : "=v"(r) : "v"(p), "n"(IMM));
  return r;
}

// Permutation within each 64-element block: stored s holds true (s>>2)+16*(s&3).
// Inverse (true c comes from stored): p(c) = (c&15)*4 + (c>>4).

// ---------------- fused fp32->bf16 conversion of all four inputs ----------------
__global__ void k_convert_all(const float* __restrict__ s, const float* __restrict__ t,
                              const float* __restrict__ w0, const float* __restrict__ w1,
                              unsigned short* __restrict__ sb, unsigned short* __restrict__ tb,
                              unsigned short* __restrict__ wb0, unsigned short* __restrict__ wb1) {
  int b = blockIdx.x;
  const float* in; unsigned short* out; int idx;
  if (b < 4096)      { in = s;  out = sb;  idx = b * 256 + threadIdx.x; }
  else if (b < 8192) { in = t;  out = tb;  idx = (b - 4096) * 256 + threadIdx.x; }
  else if (b < 9216) { in = w0; out = wb0; idx = (b - 8192) * 256 + threadIdx.x; }
  else               { in = w1; out = wb1; idx = (b - 9216) * 256 + threadIdx.x; }
  float4 v = ((const float4*)in)[idx];
  ushort4 o;
  o.x = f2bf(v.x); o.y = f2bf(v.y); o.z = f2bf(v.z); o.w = f2bf(v.w);
  ((ushort4*)out)[idx] = o;
}

// transpose fp32 target [R=NTGT][C=DIM] -> bf16 tgtT_b[n][s] = target[true(s)][n]
__global__ void k_transpose_bf16(const float* __restrict__ in, unsigned short* __restrict__ out,
                                 int R, int C) {
  __shared__ unsigned short tile[32][33];
  int c0 = blockIdx.x * 32, r0 = blockIdx.y * 32;
  int tx = threadIdx.x, ty = threadIdx.y; // 32 x 8
  for (int i = ty; i < 32; i += 8) {
    int row = r0 + i;
    int p = row & 63;
    int tr = (row & ~63) | ((p >> 2) | ((p & 3) << 4)); // true(row)
    tile[i][tx] = f2bf(in[(size_t)tr * C + c0 + tx]);
  }
  __syncthreads();
  for (int i = ty; i < 32; i += 8)
    out[(size_t)(c0 + i) * R + r0 + tx] = tile[tx][i];
}

// ---------------- finalize ----------------
// aligned = sum(P[0..3]) / rs   (z=4 split-K partials)
__global__ void k_finalize_aligned(const float* __restrict__ P, float* __restrict__ aligned,
                                   const float* __restrict__ rs) {
  const int b = blockIdx.x;
  const int lane = threadIdx.x & 63, w = threadIdx.x >> 6;
  const int src = ((lane & 15) << 2) | (lane >> 4);
  const size_t stride = (size_t)NSRC * DIM;
#pragma unroll
  for (int it = 0; it < 4; ++it) {
    int idx = b * 16 + w * 4 + it;   // 64-block index; 16 per row of DIM
    size_t base = (size_t)idx * 64;
    float r = 1.0f / rs[idx >> 4];
    float v = (P[base + lane] + P[base + stride + lane] +
               P[base + 2 * stride + lane] + P[base + 3 * stride + lane]) * r;
    aligned[base + lane] = __shfl(v, src, 64);
  }
}

// K = bf2f(Eb)/rs (un-permuted)
__global__ void k_finalize_K(const unsigned short* __restrict__ Eb, float* __restrict__ Kf,
                             const float* __restrict__ rs) {
  const int b = blockIdx.x;
  const int lane = threadIdx.x & 63, w = threadIdx.x >> 6;
  const int src = ((lane & 15) << 2) | (lane >> 4);
#pragma unroll
  for (int it = 0; it < 8; ++it) {
    int idx = b * 32 + w * 8 + it;  // 64-block index; 64 per row of NTGT
    size_t base = (size_t)idx * 64;
    float r = 1.0f / rs[idx >> 6];
    float v = bf2f(Eb[base + lane]) * r;
    Kf[base + lane] = __shfl(v, src, 64);
  }
}

// ---------------- 256x256 tile GEMM, [2][256 rows][64 k] LDS, fat tile-phases --------
// NT bf16: A [M rows][LDK k], B [N rows][LDK k]; K-chunk always 1024 (16 tiles of 64).
// LDS rows are 128 B -> each gl_lds16 instr stages 8 rows x 128 B CONTIGUOUS global
// segments (the round-6 layout's 64-B scattered segments saturated L2 request rate).
// Bank swizzle: 16-B slot' = slot ^ (row&7), folded into per-lane ds_read bases
// (2 per operand: ks0/ks1) so all fragment reads keep static offset: imms.
// 8 lanes/slot = b128 baseline -> conflict-clean. Full 64-k row staged in ONE instr
// -> swizzle never crosses a staging boundary.
// Per-tile phase: {24 ds_read; lgkm0; BAR; stage tile T+2 (8 gl_lds); MFMA x64
// (setprio); vmcnt(8); BAR}. Counted vmcnt: one tile (8 loads) stays in flight.
// EPI 0: proj +bias, permuted bf16 out, row-sumsq atomics (z selects problem)
// EPI 1: score E=exp(-sqrt(max(sqs+sqt-2c,0))/T), permuted bf16 out, row sums
// EPI 3: split-K PV (z = k-chunk), fp32 partial float4 stores (permuted cols)
template <int EPI, int LDK>
__global__ void __launch_bounds__(512, 2)
k_tile256(const unsigned short* __restrict__ A0, const unsigned short* __restrict__ B0,
          const unsigned short* __restrict__ A1, const unsigned short* __restrict__ B1,
          const float* __restrict__ bias0, const float* __restrict__ bias1,
          unsigned short* __restrict__ Cb0, unsigned short* __restrict__ Cb1,
          unsigned short* __restrict__ Eb, float* __restrict__ Cf,
          const float* __restrict__ sqs, const float* __restrict__ sqt,
          const float* __restrict__ tempPtr,
          float* __restrict__ red0, float* __restrict__ red1) {
  __shared__ unsigned short ldsA[32768]; // [2 buf][256 rows][64 k] = 64 KB
  __shared__ unsigned short ldsB[32768]; // 64 KB

  const unsigned short* A = A0;
  const unsigned short* B = B0;
  const float* bias = bias0;
  unsigned short* Cb = Cb0;
  float* red = red0;
  if constexpr (EPI == 0) {
    if (blockIdx.z) { A = A1; B = B1; bias = bias1; Cb = Cb1; red = red1; }
  }
  if constexpr (EPI == 3) { A += blockIdx.z * 1024; B += blockIdx.z * 1024; }

  // XCD-aware bijective swizzle of (x,y): all grids have nwg%8==0.
  int nbx = blockIdx.x, nby = blockIdx.y;
  {
    const int nx = gridDim.x, n = gridDim.x * gridDim.y;
    const int id = nby * nx + nbx;
    const int q = n >> 3;
    const int s = (id & 7) * q + (id >> 3);
    nbx = s % nx; nby = s / nx;
  }

  const int tid = threadIdx.x;
  const int lane = tid & 63, w = tid >> 6;   // 8 waves
  const int wm = w >> 2, wn = w & 3;         // 2 x 4
  const int fr = lane & 15, kq = lane >> 4;
  const int m0 = nby * 256, n0 = nbx * 256;

  // ---- stage addressing: group g = q*8+w covers rows g*8..g*8+7, full 64 k ----
  const int rg = lane >> 3;                       // row-in-group 0..7
  const int sk = ((lane & 7) ^ rg) * 8;           // inverse-swizzled source k (shorts)
  const size_t aS = (size_t)(m0 + w * 8 + rg) * LDK + sk;
  const size_t bS = (size_t)(n0 + w * 8 + rg) * LDK + sk;

  // ---- fragment-read bases (shorts): row*64 + swizzled-slot*8; imm adds buf/i ----
  const int eA = fr & 7;
  const lds3p baseA0 = (lds3p)ldsA + (wm * 128 + fr) * 64 + ((kq ^ eA) * 8);
  const lds3p baseA1 = (lds3p)ldsA + (wm * 128 + fr) * 64 + (((4 + kq) ^ eA) * 8);
  const lds3p baseB0 = (lds3p)ldsB + (wn * 64 + fr) * 64 + ((kq ^ eA) * 8);
  const lds3p baseB1 = (lds3p)ldsB + (wn * 64 + fr) * 64 + (((4 + kq) ^ eA) * 8);

#define STAGE(buf, tk) do { \
    gl_lds16(A + aS + (size_t)(tk),                 ldsA + (buf) * 16384 + w * 512); \
    gl_lds16(A + aS + 64 * (size_t)LDK + (tk),      ldsA + (buf) * 16384 + 4096 + w * 512); \
    gl_lds16(A + aS + 128 * (size_t)LDK + (tk),     ldsA + (buf) * 16384 + 8192 + w * 512); \
    gl_lds16(A + aS + 192 * (size_t)LDK + (tk),     ldsA + (buf) * 16384 + 12288 + w * 512); \
    gl_lds16(B + bS + (size_t)(tk),                 ldsB + (buf) * 16384 + w * 512); \
    gl_lds16(B + bS + 64 * (size_t)LDK + (tk),      ldsB + (buf) * 16384 + 4096 + w * 512); \
    gl_lds16(B + bS + 128 * (size_t)LDK + (tk),     ldsB + (buf) * 16384 + 8192 + w * 512); \
    gl_lds16(B + bS + 192 * (size_t)LDK + (tk),     ldsB + (buf) * 16384 + 12288 + w * 512); \
  } while (0)

  const fx4 fz = {0.f, 0.f, 0.f, 0.f};
  fx4 acc[8][4];
#pragma unroll
  for (int i = 0; i < 8; ++i)
#pragma unroll
    for (int j = 0; j < 4; ++j) acc[i][j] = fz;

  bf16x8 a[8][2], b[4][2];

  // byte imms: buf*32768 + i*2048 (A rows step 16*128B), j*2048 (B)
#define RD24(buf) do { \
    a[0][0] = dsr128<(buf) * 32768 +     0>(baseA0); \
    a[1][0] = dsr128<(buf) * 32768 +  2048>(baseA0); \
    a[2][0] = dsr128<(buf) * 32768 +  4096>(baseA0); \
    a[3][0] = dsr128<(buf) * 32768 +  6144>(baseA0); \
    a[4][0] = dsr128<(buf) * 32768 +  8192>(baseA0); \
    a[5][0] = dsr128<(buf) * 32768 + 10240>(baseA0); \
    a[6][0] = dsr128<(buf) * 32768 + 12288>(baseA0); \
    a[7][0] = dsr128<(buf) * 32768 + 14336>(baseA0); \
    a[0][1] = dsr128<(buf) * 32768 +     0>(baseA1); \
    a[1][1] = dsr128<(buf) * 32768 +  2048>(baseA1); \
    a[2][1] = dsr128<(buf) * 32768 +  4096>(baseA1); \
    a[3][1] = dsr128<(buf) * 32768 +  6144>(baseA1); \
    a[4][1] = dsr128<(buf) * 32768 +  8192>(baseA1); \
    a[5][1] = dsr128<(buf) * 32768 + 10240>(baseA1); \
    a[6][1] = dsr128<(buf) * 32768 + 12288>(baseA1); \
    a[7][1] = dsr128<(buf) * 32768 + 14336>(baseA1); \
    b[0][0] = dsr128<(buf) * 32768 +     0>(baseB0); \
    b[1][0] = dsr128<(buf) * 32768 +  2048>(baseB0); \
    b[2][0] = dsr128<(buf) * 32768 +  4096>(baseB0); \
    b[3][0] = dsr128<(buf) * 32768 +  6144>(baseB0); \
    b[0][1] = dsr128<(buf) * 32768 +     0>(baseB1); \
    b[1][1] = dsr128<(buf) * 32768 +  2048>(baseB1); \
    b[2][1] = dsr128<(buf) * 32768 +  4096>(baseB1); \
    b[3][1] = dsr128<(buf) * 32768 +  6144>(baseB1); \
  } while (0)

#define MFMA64() do { _Pragma("unroll") \
    for (int i = 0; i < 8; ++i) { _Pragma("unroll") \
      for (int j = 0; j < 4; ++j) { \
        acc[i][j] = __builtin_amdgcn_mfma_f32_16x16x32_bf16(a[i][0], b[j][0], acc[i][j], 0, 0, 0); \
        acc[i][j] = __builtin_amdgcn_mfma_f32_16x16x32_bf16(a[i][1], b[j][1], acc[i][j], 0, 0, 0); \
      } } } while (0)

#define SB0()   __builtin_amdgcn_sched_barrier(0)
#define BARS()  do { SB0(); __builtin_amdgcn_s_barrier(); SB0(); } while (0)
#define LGKM0() do { asm volatile("s_waitcnt lgkmcnt(0)" ::: "memory"); SB0(); } while (0)
#define VM8()   do { asm volatile("s_waitcnt vmcnt(8)" ::: "memory"); SB0(); } while (0)
#define VM0()   do { asm volatile("s_waitcnt vmcnt(0)" ::: "memory"); SB0(); } while (0)

  // Phase(T): reads retired (all waves) before stage overwrites same buf; counted
  // vmcnt(8) at end retires the PREVIOUS phase's tile (needed next phase).
#define PH_MAIN(buf, tk2) do { \
    RD24(buf); \
    LGKM0(); \
    BARS(); \
    STAGE(buf, tk2); SB0(); \
    __builtin_amdgcn_s_setprio(1); MFMA64(); __builtin_amdgcn_s_setprio(0); \
    VM8(); \
    BARS(); \
  } while (0)

  // prologue: tile0 -> buf0, tile1 -> buf1 (16 loads); vm8 -> tile0 landed
  STAGE(0, 0);
  STAGE(1, 64);
  VM8();
  BARS();

#pragma unroll 1
  for (int it = 0; it < 7; ++it) {
    PH_MAIN(0, it * 128 + 128); // consume tile 2it   (buf0); stage tile 2it+2
    PH_MAIN(1, it * 128 + 192); // consume tile 2it+1 (buf1); stage tile 2it+3
  }
  // tile 14 (buf0): no stage; vm0 retires tile-15 loads before its reads
  RD24(0);
  LGKM0();
  BARS();
  __builtin_amdgcn_s_setprio(1); MFMA64(); __builtin_amdgcn_s_setprio(0);
  VM0();
  BARS();
  // tile 15 (buf1): final
  RD24(1);
  LGKM0();
  __builtin_amdgcn_s_setprio(1); MFMA64(); __builtin_amdgcn_s_setprio(0);

  // ---------------- epilogues ----------------
  const int gcol0 = n0 + wn * 64 + fr;      // true col, + j*16
  const int scol  = n0 + wn * 64 + fr * 4;  // permuted stored col base

  if constexpr (EPI == 0) {
    // proj: +bias, permuted bf16 store, row-sumsq (of ROUNDED values) atomics
#pragma unroll
    for (int i = 0; i < 8; ++i)
#pragma unroll
      for (int r = 0; r < 4; ++r) {
        const int gm = m0 + wm * 128 + i * 16 + kq * 4 + r;
        float racc = 0.f;
        ushort4 o; unsigned short* op = (unsigned short*)&o;
#pragma unroll
        for (int j = 0; j < 4; ++j) {
          float e = acc[i][j][r] + bias[gcol0 + j * 16];
          unsigned short eb = f2bf(e);
          op[j] = eb;
          float ev = bf2f(eb);
          racc += ev * ev;
        }
        *(ushort4*)(Cb + (size_t)gm * DIM + scol) = o;
        racc += __shfl_xor(racc, 1, 64);
        racc += __shfl_xor(racc, 2, 64);
        racc += __shfl_xor(racc, 4, 64);
        racc += __shfl_xor(racc, 8, 64);
        if (fr == 0) atomicAdd(&red[gm], racc);
      }
  } else if constexpr (EPI == 1) {
    // score: E = exp(-sqrt(max(sqs+sqt-2c,0))/T), permuted bf16 store, row sums
    const float invT = 1.0f / tempPtr[0];
#pragma unroll
    for (int i = 0; i < 8; ++i)
#pragma unroll
      for (int r = 0; r < 4; ++r) {
        const int gm = m0 + wm * 128 + i * 16 + kq * 4 + r;
        const float si = sqs[gm];
        float racc = 0.f;
        ushort4 o; unsigned short* op = (unsigned short*)&o;
#pragma unroll
        for (int j = 0; j < 4; ++j) {
          float d2 = si + sqt[gcol0 + j * 16] - 2.0f * acc[i][j][r];
          float c = sqrtf(fmaxf(d2, 0.0f));
          unsigned short eb = f2bf(__expf(-c * invT));
          op[j] = eb;
          racc += bf2f(eb);
        }
        *(ushort4*)(Eb + (size_t)gm * NTGT + scol) = o;
        racc += __shfl_xor(racc, 1, 64);
        racc += __shfl_xor(racc, 2, 64);
        racc += __shfl_xor(racc, 4, 64);
        racc += __shfl_xor(racc, 8, 64);
        if (fr == 0) atomicAdd(&red[gm], racc);
      }
  } else {
    // split-K PV: fp32 partials, permuted float4 stores
    float* Pz = Cf + (size_t)blockIdx.z * NSRC * DIM;
#pragma unroll
    for (int i = 0; i < 8; ++i)
#pragma unroll
      for (int r = 0; r < 4; ++r) {
        const int gm = m0 + wm * 128 + i * 16 + kq * 4 + r;
        float4 v = make_float4(acc[i][0][r], acc[i][1][r], acc[i][2][r], acc[i][3][r]);
        *(float4*)(Pz + (size_t)gm * DIM + scol) = v;
      }
  }
#undef STAGE
#undef RD24
#undef MFMA64
#undef PH_MAIN
#undef SB0
#undef BARS
#undef LGKM0
#undef VM8
#undef VM0
}

// ---------------- launch ----------------
extern "C" void kernel_launch(void* const* d_in, const int* in_sizes, int n_in,
                              void* d_out, int out_size, void* d_ws, size_t ws_size,
                              hipStream_t stream) {
  const float* source = (const float*)d_in[0];
  const float* target = (const float*)d_in[1];
  const float* W_src  = (const float*)d_in[2];
  const float* b_src  = (const float*)d_in[3];
  const float* W_tgt  = (const float*)d_in[4];
  const float* b_tgt  = (const float*)d_in[5];
  const float* temp   = (const float*)d_in[6];

  float* out     = (float*)d_out;
  float* aligned = out;                         // [NSRC][DIM]
  float* Kout    = out + (size_t)NSRC * DIM;    // final K; staging for split-K partials
  float* parts   = Kout;                        // 4 x [NSRC][DIM] fp32 = exactly 64 MB

  char* ws = (char*)d_ws;
  unsigned short* src_b  = (unsigned short*)(ws + 0);
  unsigned short* tgt_b  = (unsigned short*)(ws + 8388608);
  unsigned short* Wsrc_b = (unsigned short*)(ws + 16777216);
  unsigned short* Wtgt_b = (unsigned short*)(ws + 18874368);
  unsigned short* sp_b   = (unsigned short*)(ws + 20971520);
  unsigned short* tp_b   = (unsigned short*)(ws + 29360128);
  unsigned short* tgtT_b = (unsigned short*)(ws + 37748736);
  unsigned short* E_b    = (unsigned short*)(ws + 46137344); // 32 MB
  float* sq_s  = (float*)(ws + 79691776);                    // 16 KB
  float* sq_t  = (float*)(ws + 79708160);                    // 16 KB
  float* rsums = (float*)(ws + 79724544);                    // 16 KB

  // 0) zero sq_s, sq_t, rsums (contiguous 48 KB)
  hipMemsetAsync(sq_s, 0, 3 * NSRC * sizeof(float), stream);

  // 1) conversions + permuted target transpose
  k_convert_all<<<10240, 256, 0, stream>>>(source, target, W_src, W_tgt,
                                           src_b, tgt_b, Wsrc_b, Wtgt_b);
  k_transpose_bf16<<<dim3(DIM / 32, NTGT / 32), dim3(32, 8), 0, stream>>>(target, tgtT_b, NTGT, DIM);

  // 2) both projections (z selects problem); outputs permuted in DIM; row-sumsq fused
  k_tile256<0, DIM><<<dim3(DIM / 256, NSRC / 256, 2), 512, 0, stream>>>(
      src_b, Wsrc_b, tgt_b, Wtgt_b, b_src, b_tgt, sp_b, tp_b,
      nullptr, nullptr, nullptr, nullptr, nullptr, sq_s, sq_t);

  // 3) score: E bf16 (permuted in NTGT) -> ws, row sums -> rsums
  k_tile256<1, DIM><<<dim3(NTGT / 256, NSRC / 256, 1), 512, 0, stream>>>(
      sp_b, tp_b, nullptr, nullptr, nullptr, nullptr, nullptr, nullptr,
      E_b, nullptr, sq_s, sq_t, temp, rsums, nullptr);

  // 4) E @ target: split-K x4 (chunk=1024), permuted float4 partials into d_out K region
  k_tile256<3, NTGT><<<dim3(DIM / 256, NSRC / 256, 4), 512, 0, stream>>>(
      E_b, tgtT_b, nullptr, nullptr, nullptr, nullptr, nullptr, nullptr,
      nullptr, parts, nullptr, nullptr, nullptr, nullptr, nullptr);

  // 5) finalize: aligned first (reads parts), then K (overwrites parts region)
  k_finalize_aligned<<<4096, 256, 0, stream>>>(parts, aligned, rsums);
  k_finalize_K<<<8192, 256, 0, stream>>>(E_b, Kout, rsums);
}

// Round 8
// 261.988 us; speedup vs baseline: 1.0574x; 1.0574x over previous
//
#include <hip/hip_runtime.h>
#include <stdint.h>

#define DIM  1024
#define NSRC 4096
#define NTGT 4096

typedef __bf16 bf16_t;
typedef bf16_t bf16x8 __attribute__((ext_vector_type(8)));
typedef float  fx4    __attribute__((ext_vector_type(4)));

static __device__ __forceinline__ unsigned short f2bf(float f) {
  union { float f; uint32_t u; } v; v.f = f;
  return (unsigned short)((v.u + 0x7FFFu + ((v.u >> 16) & 1u)) >> 16);
}
static __device__ __forceinline__ float bf2f(unsigned short h) {
  union { uint32_t u; float f; } v; v.u = ((uint32_t)h) << 16;
  return v.f;
}

// async global->LDS, 16B per lane; lds dest is wave-uniform base + lane*16
static __device__ __forceinline__ void gl_lds16(const unsigned short* g, unsigned short* l) {
  __builtin_amdgcn_global_load_lds(
      (__attribute__((address_space(1))) const void*)g,
      (__attribute__((address_space(3))) void*)l, 16, 0, 0);
}

typedef const __attribute__((address_space(3))) unsigned short* lds3p;

// inline-asm ds_read_b128 with compile-time byte offset immediate.
template <int IMM>
static __device__ __forceinline__ bf16x8 dsr128(lds3p p) {
  bf16x8 r;
  asm volatile("ds_read_b128 %0, %1 offset:%2" : "=v"(r) : "v"(p), "n"(IMM));
  return r;
}

// Permutation within each 64-element block: stored s holds true (s>>2)+16*(s&3).
// Inverse (true c comes from stored): p(c) = (c&15)*4 + (c>>4).

// ---------------- fused fp32->bf16 conversion of all four inputs ----------------
__global__ void k_convert_all(const float* __restrict__ s, const float* __restrict__ t,
                              const float* __restrict__ w0, const float* __restrict__ w1,
                              unsigned short* __restrict__ sb, unsigned short* __restrict__ tb,
                              unsigned short* __restrict__ wb0, unsigned short* __restrict__ wb1) {
  int b = blockIdx.x;
  const float* in; unsigned short* out; int idx;
  if (b < 4096)      { in = s;  out = sb;  idx = b * 256 + threadIdx.x; }
  else if (b < 8192) { in = t;  out = tb;  idx = (b - 4096) * 256 + threadIdx.x; }
  else if (b < 9216) { in = w0; out = wb0; idx = (b - 8192) * 256 + threadIdx.x; }
  else               { in = w1; out = wb1; idx = (b - 9216) * 256 + threadIdx.x; }
  float4 v = ((const float4*)in)[idx];
  ushort4 o;
  o.x = f2bf(v.x); o.y = f2bf(v.y); o.z = f2bf(v.z); o.w = f2bf(v.w);
  ((ushort4*)out)[idx] = o;
}

// transpose fp32 target [R=NTGT][C=DIM] -> bf16 tgtT_b[n][s] = target[true(s)][n]
__global__ void k_transpose_bf16(const float* __restrict__ in, unsigned short* __restrict__ out,
                                 int R, int C) {
  __shared__ unsigned short tile[32][33];
  int c0 = blockIdx.x * 32, r0 = blockIdx.y * 32;
  int tx = threadIdx.x, ty = threadIdx.y; // 32 x 8
  for (int i = ty; i < 32; i += 8) {
    int row = r0 + i;
    int p = row & 63;
    int tr = (row & ~63) | ((p >> 2) | ((p & 3) << 4)); // true(row)
    tile[i][tx] = f2bf(in[(size_t)tr * C + c0 + tx]);
  }
  __syncthreads();
  for (int i = ty; i < 32; i += 8)
    out[(size_t)(c0 + i) * R + r0 + tx] = tile[tx][i];
}

// ---------------- finalize ----------------
// aligned = sum(P[0..1]) / rs   (z=2 split-K partials)
__global__ void k_finalize_aligned(const float* __restrict__ P, float* __restrict__ aligned,
                                   const float* __restrict__ rs) {
  const int b = blockIdx.x;
  const int lane = threadIdx.x & 63, w = threadIdx.x >> 6;
  const int src = ((lane & 15) << 2) | (lane >> 4);
  const size_t stride = (size_t)NSRC * DIM;
#pragma unroll
  for (int it = 0; it < 4; ++it) {
    int idx = b * 16 + w * 4 + it;   // 64-block index; 16 per row of DIM
    size_t base = (size_t)idx * 64;
    float r = 1.0f / rs[idx >> 4];
    float v = (P[base + lane] + P[base + stride + lane]) * r;
    aligned[base + lane] = __shfl(v, src, 64);
  }
}

// K = bf2f(Eb)/rs (un-permuted)
__global__ void k_finalize_K(const unsigned short* __restrict__ Eb, float* __restrict__ Kf,
                             const float* __restrict__ rs) {
  const int b = blockIdx.x;
  const int lane = threadIdx.x & 63, w = threadIdx.x >> 6;
  const int src = ((lane & 15) << 2) | (lane >> 4);
#pragma unroll
  for (int it = 0; it < 8; ++it) {
    int idx = b * 32 + w * 8 + it;  // 64-block index; 64 per row of NTGT
    size_t base = (size_t)idx * 64;
    float r = 1.0f / rs[idx >> 6];
    float v = bf2f(Eb[base + lane]) * r;
    Kf[base + lane] = __shfl(v, src, 64);
  }
}

// ---------------- 128x128 tile GEMM, 2 blocks/CU, [2][128 rows][64 k] LDS ----------
// The 256x256 single-block/CU versions were pinned at MfmaUtil 22% regardless of
// schedule: one lockstep block alternates LDS-read and MFMA windows with nothing to
// fill the idle pipe. 128x128 / 256-thread / 64-KiB-LDS gives 2 independent blocks
// per CU -> windows of one block overlap the other's (m114 mechanism).
// NT bf16: A [M][LDK], B [N][LDK]; KT tiles of 64 k.
// Stage: 8 gl_lds16/wave/tile, each 8 rows x 128 B contiguous; source col
// pre-swizzled sk=((lane&7)^rg)*8. ds_read: slot' = slot ^ (row&7) folded into
// per-lane bases (conflict-clean: 8 lanes/slot = b128 baseline; XOR self-inverts
// so fragments land true-k-aligned).
// Schedule/tile: {prefetch next (8 gl_lds); vmcnt(8) [counted: waits PREVIOUS
// tile only]; bar; 16 ds_read; lgkm0; 32 MFMA; bar}. 2-tile unroll keeps imms static.
// EPI 0: proj +bias, permuted bf16 out, row-sumsq atomics (z selects problem)
// EPI 1: score E=exp(-sqrt(max(sqs+sqt-2c,0))/T), permuted bf16 out, row sums
// EPI 3: split-K PV (z = k-chunk of 2048), fp32 partial float4 stores (permuted)
template <int EPI, int LDK, int KT>
__global__ void __launch_bounds__(256, 2)
k_tile128(const unsigned short* __restrict__ A0, const unsigned short* __restrict__ B0,
          const unsigned short* __restrict__ A1, const unsigned short* __restrict__ B1,
          const float* __restrict__ bias0, const float* __restrict__ bias1,
          unsigned short* __restrict__ Cb0, unsigned short* __restrict__ Cb1,
          unsigned short* __restrict__ Eb, float* __restrict__ Cf,
          const float* __restrict__ sqs, const float* __restrict__ sqt,
          const float* __restrict__ tempPtr,
          float* __restrict__ red0, float* __restrict__ red1) {
  __shared__ unsigned short ldsA[16384]; // [2 buf][128 rows][64 k] = 32 KB
  __shared__ unsigned short ldsB[16384]; // 32 KB

  const unsigned short* A = A0;
  const unsigned short* B = B0;
  const float* bias = bias0;
  unsigned short* Cb = Cb0;
  float* red = red0;
  if constexpr (EPI == 0) {
    if (blockIdx.z) { A = A1; B = B1; bias = bias1; Cb = Cb1; red = red1; }
  }
  if constexpr (EPI == 3) { A += blockIdx.z * 2048; B += blockIdx.z * 2048; }

  // XCD-aware bijective swizzle of (x,y): all grids have (gx*gy)%8==0.
  int nbx = blockIdx.x, nby = blockIdx.y;
  {
    const int nx = gridDim.x, n = gridDim.x * gridDim.y;
    const int id = nby * nx + nbx;
    const int q = n >> 3;
    const int s = (id & 7) * q + (id >> 3);
    nbx = s % nx; nby = s / nx;
  }

  const int tid = threadIdx.x;
  const int lane = tid & 63, w = tid >> 6;   // 4 waves
  const int wm = w >> 1, wn = w & 1;         // 2 x 2
  const int fr = lane & 15, kq = lane >> 4;
  const int m0 = nby * 128, n0 = nbx * 128;

  // ---- stage addressing: group g = q*4+w covers rows g*8..g*8+7, full 64 k ----
  const int rg = lane >> 3;                       // row-in-group 0..7
  const int sk = ((lane & 7) ^ rg) * 8;           // inverse-swizzled source k (shorts)
  const size_t aS = (size_t)(m0 + w * 8 + rg) * LDK + sk;
  const size_t bS = (size_t)(n0 + w * 8 + rg) * LDK + sk;

  // ---- fragment-read bases (shorts): row*64 + swizzled-slot*8 ----
  const int eA = fr & 7;
  const lds3p baseA0 = (lds3p)ldsA + (wm * 64 + fr) * 64 + ((kq ^ eA) * 8);
  const lds3p baseA1 = (lds3p)ldsA + (wm * 64 + fr) * 64 + (((4 + kq) ^ eA) * 8);
  const lds3p baseB0 = (lds3p)ldsB + (wn * 64 + fr) * 64 + ((kq ^ eA) * 8);
  const lds3p baseB1 = (lds3p)ldsB + (wn * 64 + fr) * 64 + (((4 + kq) ^ eA) * 8);

  // wave w stages groups {w, 4+w, 8+w, 12+w} for A and B (8 gl_lds per tile)
#define STAGE(buf, tk) do { \
    gl_lds16(A + aS + (size_t)(tk),              ldsA + (buf) * 8192 + w * 512); \
    gl_lds16(A + aS + 32 * (size_t)LDK + (tk),   ldsA + (buf) * 8192 + 2048 + w * 512); \
    gl_lds16(A + aS + 64 * (size_t)LDK + (tk),   ldsA + (buf) * 8192 + 4096 + w * 512); \
    gl_lds16(A + aS + 96 * (size_t)LDK + (tk),   ldsA + (buf) * 8192 + 6144 + w * 512); \
    gl_lds16(B + bS + (size_t)(tk),              ldsB + (buf) * 8192 + w * 512); \
    gl_lds16(B + bS + 32 * (size_t)LDK + (tk),   ldsB + (buf) * 8192 + 2048 + w * 512); \
    gl_lds16(B + bS + 64 * (size_t)LDK + (tk),   ldsB + (buf) * 8192 + 4096 + w * 512); \
    gl_lds16(B + bS + 96 * (size_t)LDK + (tk),   ldsB + (buf) * 8192 + 6144 + w * 512); \
  } while (0)

  const fx4 fz = {0.f, 0.f, 0.f, 0.f};
  fx4 acc[4][4];
#pragma unroll
  for (int i = 0; i < 4; ++i)
#pragma unroll
    for (int j = 0; j < 4; ++j) acc[i][j] = fz;

  bf16x8 a[4][2], b[4][2];

  // byte imms: buf*16384 + i*2048 (16 rows x 128 B)
#define RD16(buf) do { \
    a[0][0] = dsr128<(buf) * 16384 +    0>(baseA0); \
    a[1][0] = dsr128<(buf) * 16384 + 2048>(baseA0); \
    a[2][0] = dsr128<(buf) * 16384 + 4096>(baseA0); \
    a[3][0] = dsr128<(buf) * 16384 + 6144>(baseA0); \
    a[0][1] = dsr128<(buf) * 16384 +    0>(baseA1); \
    a[1][1] = dsr128<(buf) * 16384 + 2048>(baseA1); \
    a[2][1] = dsr128<(buf) * 16384 + 4096>(baseA1); \
    a[3][1] = dsr128<(buf) * 16384 + 6144>(baseA1); \
    b[0][0] = dsr128<(buf) * 16384 +    0>(baseB0); \
    b[1][0] = dsr128<(buf) * 16384 + 2048>(baseB0); \
    b[2][0] = dsr128<(buf) * 16384 + 4096>(baseB0); \
    b[3][0] = dsr128<(buf) * 16384 + 6144>(baseB0); \
    b[0][1] = dsr128<(buf) * 16384 +    0>(baseB1); \
    b[1][1] = dsr128<(buf) * 16384 + 2048>(baseB1); \
    b[2][1] = dsr128<(buf) * 16384 + 4096>(baseB1); \
    b[3][1] = dsr128<(buf) * 16384 + 6144>(baseB1); \
  } while (0)

#define MFMA32() do { _Pragma("unroll") \
    for (int i = 0; i < 4; ++i) { _Pragma("unroll") \
      for (int j = 0; j < 4; ++j) { \
        acc[i][j] = __builtin_amdgcn_mfma_f32_16x16x32_bf16(a[i][0], b[j][0], acc[i][j], 0, 0, 0); \
        acc[i][j] = __builtin_amdgcn_mfma_f32_16x16x32_bf16(a[i][1], b[j][1], acc[i][j], 0, 0, 0); \
      } } } while (0)

#define SB0()   __builtin_amdgcn_sched_barrier(0)
#define BARS()  do { SB0(); __builtin_amdgcn_s_barrier(); SB0(); } while (0)
#define LGKM0() do { asm volatile("s_waitcnt lgkmcnt(0)" ::: "memory"); SB0(); } while (0)
#define VM8()   do { asm volatile("s_waitcnt vmcnt(8)" ::: "memory"); SB0(); } while (0)
#define VM0()   do { asm volatile("s_waitcnt vmcnt(0)" ::: "memory"); SB0(); } while (0)

#define HALF(buf, nbuf, tk) do { \
    STAGE(nbuf, tk); \
    VM8(); BARS(); \
    RD16(buf); LGKM0(); \
    __builtin_amdgcn_s_setprio(1); MFMA32(); __builtin_amdgcn_s_setprio(0); \
    BARS(); \
  } while (0)

  // prologue: tile0 -> buf0
  STAGE(0, 0);
#pragma unroll 1
  for (int t = 0; t < KT / 2 - 1; ++t) {
    HALF(0, 1, (2 * t + 1) * 64); // consume tile 2t (buf0); prefetch 2t+1 -> buf1
    HALF(1, 0, (2 * t + 2) * 64); // consume tile 2t+1 (buf1); prefetch 2t+2 -> buf0
  }
  // tile KT-2 (buf0), prefetch final tile KT-1 -> buf1
  HALF(0, 1, (KT - 1) * 64);
  // final tile KT-1 (buf1): no prefetch; drain
  VM0(); BARS();
  RD16(1); LGKM0();
  __builtin_amdgcn_s_setprio(1); MFMA32(); __builtin_amdgcn_s_setprio(0);

  // ---------------- epilogues ----------------
  const int gcol0 = n0 + wn * 64 + fr;      // true col, + j*16
  const int scol  = n0 + wn * 64 + fr * 4;  // permuted stored col base

  if constexpr (EPI == 0) {
    // proj: +bias, permuted bf16 store, row-sumsq (of ROUNDED values) atomics
#pragma unroll
    for (int i = 0; i < 4; ++i)
#pragma unroll
      for (int r = 0; r < 4; ++r) {
        const int gm = m0 + wm * 64 + i * 16 + kq * 4 + r;
        float racc = 0.f;
        ushort4 o; unsigned short* op = (unsigned short*)&o;
#pragma unroll
        for (int j = 0; j < 4; ++j) {
          float e = acc[i][j][r] + bias[gcol0 + j * 16];
          unsigned short eb = f2bf(e);
          op[j] = eb;
          float ev = bf2f(eb);
          racc += ev * ev;
        }
        *(ushort4*)(Cb + (size_t)gm * DIM + scol) = o;
        racc += __shfl_xor(racc, 1, 64);
        racc += __shfl_xor(racc, 2, 64);
        racc += __shfl_xor(racc, 4, 64);
        racc += __shfl_xor(racc, 8, 64);
        if (fr == 0) atomicAdd(&red[gm], racc);
      }
  } else if constexpr (EPI == 1) {
    // score: E = exp(-sqrt(max(sqs+sqt-2c,0))/T), permuted bf16 store, row sums
    const float invT = 1.0f / tempPtr[0];
#pragma unroll
    for (int i = 0; i < 4; ++i)
#pragma unroll
      for (int r = 0; r < 4; ++r) {
        const int gm = m0 + wm * 64 + i * 16 + kq * 4 + r;
        const float si = sqs[gm];
        float racc = 0.f;
        ushort4 o; unsigned short* op = (unsigned short*)&o;
#pragma unroll
        for (int j = 0; j < 4; ++j) {
          float d2 = si + sqt[gcol0 + j * 16] - 2.0f * acc[i][j][r];
          float c = sqrtf(fmaxf(d2, 0.0f));
          unsigned short eb = f2bf(__expf(-c * invT));
          op[j] = eb;
          racc += bf2f(eb);
        }
        *(ushort4*)(Eb + (size_t)gm * NTGT + scol) = o;
        racc += __shfl_xor(racc, 1, 64);
        racc += __shfl_xor(racc, 2, 64);
        racc += __shfl_xor(racc, 4, 64);
        racc += __shfl_xor(racc, 8, 64);
        if (fr == 0) atomicAdd(&red[gm], racc);
      }
  } else {
    // split-K PV: fp32 partials, permuted float4 stores
    float* Pz = Cf + (size_t)blockIdx.z * NSRC * DIM;
#pragma unroll
    for (int i = 0; i < 4; ++i)
#pragma unroll
      for (int r = 0; r < 4; ++r) {
        const int gm = m0 + wm * 64 + i * 16 + kq * 4 + r;
        float4 v = make_float4(acc[i][0][r], acc[i][1][r], acc[i][2][r], acc[i][3][r]);
        *(float4*)(Pz + (size_t)gm * DIM + scol) = v;
      }
  }
#undef STAGE
#undef RD16
#undef MFMA32
#undef HALF
#undef SB0
#undef BARS
#undef LGKM0
#undef VM8
#undef VM0
}

// ---------------- launch ----------------
extern "C" void kernel_launch(void* const* d_in, const int* in_sizes, int n_in,
                              void* d_out, int out_size, void* d_ws, size_t ws_size,
                              hipStream_t stream) {
  const float* source = (const float*)d_in[0];
  const float* target = (const float*)d_in[1];
  const float* W_src  = (const float*)d_in[2];
  const float* b_src  = (const float*)d_in[3];
  const float* W_tgt  = (const float*)d_in[4];
  const float* b_tgt  = (const float*)d_in[5];
  const float* temp   = (const float*)d_in[6];

  float* out     = (float*)d_out;
  float* aligned = out;                         // [NSRC][DIM]
  float* Kout    = out + (size_t)NSRC * DIM;    // final K; staging for split-K partials
  float* parts   = Kout;                        // 2 x [NSRC][DIM] fp32 = 32 MB

  char* ws = (char*)d_ws;
  unsigned short* src_b  = (unsigned short*)(ws + 0);
  unsigned short* tgt_b  = (unsigned short*)(ws + 8388608);
  unsigned short* Wsrc_b = (unsigned short*)(ws + 16777216);
  unsigned short* Wtgt_b = (unsigned short*)(ws + 18874368);
  unsigned short* sp_b   = (unsigned short*)(ws + 20971520);
  unsigned short* tp_b   = (unsigned short*)(ws + 29360128);
  unsigned short* tgtT_b = (unsigned short*)(ws + 37748736);
  unsigned short* E_b    = (unsigned short*)(ws + 46137344); // 32 MB
  float* sq_s  = (float*)(ws + 79691776);                    // 16 KB
  float* sq_t  = (float*)(ws + 79708160);                    // 16 KB
  float* rsums = (float*)(ws + 79724544);                    // 16 KB

  // 0) zero sq_s, sq_t, rsums (contiguous 48 KB)
  hipMemsetAsync(sq_s, 0, 3 * NSRC * sizeof(float), stream);

  // 1) conversions + permuted target transpose
  k_convert_all<<<10240, 256, 0, stream>>>(source, target, W_src, W_tgt,
                                           src_b, tgt_b, Wsrc_b, Wtgt_b);
  k_transpose_bf16<<<dim3(DIM / 32, NTGT / 32), dim3(32, 8), 0, stream>>>(target, tgtT_b, NTGT, DIM);

  // 2) both projections (z selects problem); outputs permuted in DIM; row-sumsq fused
  k_tile128<0, DIM, 16><<<dim3(DIM / 128, NSRC / 128, 2), 256, 0, stream>>>(
      src_b, Wsrc_b, tgt_b, Wtgt_b, b_src, b_tgt, sp_b, tp_b,
      nullptr, nullptr, nullptr, nullptr, nullptr, sq_s, sq_t);

  // 3) score: E bf16 (permuted in NTGT) -> ws, row sums -> rsums
  k_tile128<1, DIM, 16><<<dim3(NTGT / 128, NSRC / 128, 1), 256, 0, stream>>>(
      sp_b, tp_b, nullptr, nullptr, nullptr, nullptr, nullptr, nullptr,
      E_b, nullptr, sq_s, sq_t, temp, rsums, nullptr);

  // 4) E @ target: split-K x2 (chunk=2048), permuted float4 partials into d_out K region
  k_tile128<3, NTGT, 32><<<dim3(DIM / 128, NSRC / 128, 2), 256, 0, stream>>>(
      E_b, tgtT_b, nullptr, nullptr, nullptr, nullptr, nullptr, nullptr,
      nullptr, parts, nullptr, nullptr, nullptr, nullptr, nullptr);

  // 5) finalize: aligned first (reads parts), then K (overwrites parts region)
  k_finalize_aligned<<<4096, 256, 0, stream>>>(parts, aligned, rsums);
  k_finalize_K<<<8192, 256, 0, stream>>>(E_b, Kout, rsums);
}

// Round 9
// 257.883 us; speedup vs baseline: 1.0742x; 1.0159x over previous
//
#include <hip/hip_runtime.h>
#include <stdint.h>

#define DIM  1024
#define NSRC 4096
#define NTGT 4096

typedef __bf16 bf16_t;
typedef bf16_t bf16x8 __attribute__((ext_vector_type(8)));
typedef float  fx4    __attribute__((ext_vector_type(4)));

static __device__ __forceinline__ unsigned short f2bf(float f) {
  union { float f; uint32_t u; } v; v.f = f;
  return (unsigned short)((v.u + 0x7FFFu + ((v.u >> 16) & 1u)) >> 16);
}
static __device__ __forceinline__ float bf2f(unsigned short h) {
  union { uint32_t u; float f; } v; v.u = ((uint32_t)h) << 16;
  return v.f;
}

// async global->LDS, 16B per lane; lds dest is wave-uniform base + lane*16
static __device__ __forceinline__ void gl_lds16(const unsigned short* g, unsigned short* l) {
  __builtin_amdgcn_global_load_lds(
      (__attribute__((address_space(1))) const void*)g,
      (__attribute__((address_space(3))) void*)l, 16, 0, 0);
}

typedef const __attribute__((address_space(3))) unsigned short* lds3p;

// inline-asm ds_read_b128 with compile-time byte offset immediate.
template <int IMM>
static __device__ __forceinline__ bf16x8 dsr128(lds3p p) {
  bf16x8 r;
  asm volatile("ds_read_b128 %0, %1 offset:%2" : "=v"(r) : "v"(p), "n"(IMM));
  return r;
}

// Permutation within each 64-element block: stored s holds true (s>>2)+16*(s&3).
// Inverse (true c comes from stored): p(c) = (c&15)*4 + (c>>4).

// ---------------- fused fp32->bf16 conversion of all four inputs ----------------
__global__ void k_convert_all(const float* __restrict__ s, const float* __restrict__ t,
                              const float* __restrict__ w0, const float* __restrict__ w1,
                              unsigned short* __restrict__ sb, unsigned short* __restrict__ tb,
                              unsigned short* __restrict__ wb0, unsigned short* __restrict__ wb1) {
  int b = blockIdx.x;
  const float* in; unsigned short* out; int idx;
  if (b < 4096)      { in = s;  out = sb;  idx = b * 256 + threadIdx.x; }
  else if (b < 8192) { in = t;  out = tb;  idx = (b - 4096) * 256 + threadIdx.x; }
  else if (b < 9216) { in = w0; out = wb0; idx = (b - 8192) * 256 + threadIdx.x; }
  else               { in = w1; out = wb1; idx = (b - 9216) * 256 + threadIdx.x; }
  float4 v = ((const float4*)in)[idx];
  ushort4 o;
  o.x = f2bf(v.x); o.y = f2bf(v.y); o.z = f2bf(v.z); o.w = f2bf(v.w);
  ((ushort4*)out)[idx] = o;
}

// transpose fp32 target [R=NTGT][C=DIM] -> bf16 tgtT_b[n][s] = target[true(s)][n]
__global__ void k_transpose_bf16(const float* __restrict__ in, unsigned short* __restrict__ out,
                                 int R, int C) {
  __shared__ unsigned short tile[32][33];
  int c0 = blockIdx.x * 32, r0 = blockIdx.y * 32;
  int tx = threadIdx.x, ty = threadIdx.y; // 32 x 8
  for (int i = ty; i < 32; i += 8) {
    int row = r0 + i;
    int p = row & 63;
    int tr = (row & ~63) | ((p >> 2) | ((p & 3) << 4)); // true(row)
    tile[i][tx] = f2bf(in[(size_t)tr * C + c0 + tx]);
  }
  __syncthreads();
  for (int i = ty; i < 32; i += 8)
    out[(size_t)(c0 + i) * R + r0 + tx] = tile[tx][i];
}

// ---------------- finalize ----------------
// aligned = sum(P[0..1]) / rs   (z=2 split-K partials)
__global__ void k_finalize_aligned(const float* __restrict__ P, float* __restrict__ aligned,
                                   const float* __restrict__ rs) {
  const int b = blockIdx.x;
  const int lane = threadIdx.x & 63, w = threadIdx.x >> 6;
  const int src = ((lane & 15) << 2) | (lane >> 4);
  const size_t stride = (size_t)NSRC * DIM;
#pragma unroll
  for (int it = 0; it < 4; ++it) {
    int idx = b * 16 + w * 4 + it;   // 64-block index; 16 per row of DIM
    size_t base = (size_t)idx * 64;
    float r = 1.0f / rs[idx >> 4];
    float v = (P[base + lane] + P[base + stride + lane]) * r;
    aligned[base + lane] = __shfl(v, src, 64);
  }
}

// K = bf2f(Eb)/rs (un-permuted)
__global__ void k_finalize_K(const unsigned short* __restrict__ Eb, float* __restrict__ Kf,
                             const float* __restrict__ rs) {
  const int b = blockIdx.x;
  const int lane = threadIdx.x & 63, w = threadIdx.x >> 6;
  const int src = ((lane & 15) << 2) | (lane >> 4);
#pragma unroll
  for (int it = 0; it < 8; ++it) {
    int idx = b * 32 + w * 8 + it;  // 64-block index; 64 per row of NTGT
    size_t base = (size_t)idx * 64;
    float r = 1.0f / rs[idx >> 6];
    float v = bf2f(Eb[base + lane]) * r;
    Kf[base + lane] = __shfl(v, src, 64);
  }
}

// ---------------- 128x128 tile GEMM, 2 blocks/CU, [2][128 rows][64 k] LDS ----------
// Identical to round 8 EXCEPT the inner consume step: instead of {16 ds_read;
// lgkmcnt(0); 32 MFMA} (which parks every wave for the full CU-wide LDS burst,
// then runs all MFMAs with LDS idle -> fixed ~2300cyc/phase, MfmaUtil 22%), the
// LADDER issues reads B-first then descends counted waits:
//   lgkm(6)->row0, lgkm(4)->row1, lgkm(2)->row2, lgkm(0)->row3
// DS retires in-order per wave, so each wave starts MFMAs when 10/16 reads have
// landed and drains the rest under compute. sched_barrier(0) after each wait
// (rule: compiler hoists reg-only MFMA past asm lgkm waits otherwise).
// NT bf16: A [M][LDK], B [N][LDK]; KT tiles of 64 k. Stage: 8 gl_lds16/wave/tile,
// 8 rows x 128 B contiguous; source col pre-swizzled sk=((lane&7)^rg)*8; ds_read
// slot' = slot ^ (row&7) folded into per-lane bases (conflict-clean, self-inverse).
// vmcnt(8): counted, waits the PREVIOUS tile's stage only.
// EPI 0: proj +bias, permuted bf16 out, row-sumsq atomics (z selects problem)
// EPI 1: score E=exp(-sqrt(max(sqs+sqt-2c,0))/T), permuted bf16 out, row sums
// EPI 3: split-K PV (z = k-chunk of 2048), fp32 partial float4 stores (permuted)
template <int EPI, int LDK, int KT>
__global__ void __launch_bounds__(256, 2)
k_tile128(const unsigned short* __restrict__ A0, const unsigned short* __restrict__ B0,
          const unsigned short* __restrict__ A1, const unsigned short* __restrict__ B1,
          const float* __restrict__ bias0, const float* __restrict__ bias1,
          unsigned short* __restrict__ Cb0, unsigned short* __restrict__ Cb1,
          unsigned short* __restrict__ Eb, float* __restrict__ Cf,
          const float* __restrict__ sqs, const float* __restrict__ sqt,
          const float* __restrict__ tempPtr,
          float* __restrict__ red0, float* __restrict__ red1) {
  __shared__ unsigned short ldsA[16384]; // [2 buf][128 rows][64 k] = 32 KB
  __shared__ unsigned short ldsB[16384]; // 32 KB

  const unsigned short* A = A0;
  const unsigned short* B = B0;
  const float* bias = bias0;
  unsigned short* Cb = Cb0;
  float* red = red0;
  if constexpr (EPI == 0) {
    if (blockIdx.z) { A = A1; B = B1; bias = bias1; Cb = Cb1; red = red1; }
  }
  if constexpr (EPI == 3) { A += blockIdx.z * 2048; B += blockIdx.z * 2048; }

  // XCD-aware bijective swizzle of (x,y): all grids have (gx*gy)%8==0.
  int nbx = blockIdx.x, nby = blockIdx.y;
  {
    const int nx = gridDim.x, n = gridDim.x * gridDim.y;
    const int id = nby * nx + nbx;
    const int q = n >> 3;
    const int s = (id & 7) * q + (id >> 3);
    nbx = s % nx; nby = s / nx;
  }

  const int tid = threadIdx.x;
  const int lane = tid & 63, w = tid >> 6;   // 4 waves
  const int wm = w >> 1, wn = w & 1;         // 2 x 2
  const int fr = lane & 15, kq = lane >> 4;
  const int m0 = nby * 128, n0 = nbx * 128;

  // ---- stage addressing: group g = q*4+w covers rows g*8..g*8+7, full 64 k ----
  const int rg = lane >> 3;                       // row-in-group 0..7
  const int sk = ((lane & 7) ^ rg) * 8;           // inverse-swizzled source k (shorts)
  const size_t aS = (size_t)(m0 + w * 8 + rg) * LDK + sk;
  const size_t bS = (size_t)(n0 + w * 8 + rg) * LDK + sk;

  // ---- fragment-read bases (shorts): row*64 + swizzled-slot*8 ----
  const int eA = fr & 7;
  const lds3p baseA0 = (lds3p)ldsA + (wm * 64 + fr) * 64 + ((kq ^ eA) * 8);
  const lds3p baseA1 = (lds3p)ldsA + (wm * 64 + fr) * 64 + (((4 + kq) ^ eA) * 8);
  const lds3p baseB0 = (lds3p)ldsB + (wn * 64 + fr) * 64 + ((kq ^ eA) * 8);
  const lds3p baseB1 = (lds3p)ldsB + (wn * 64 + fr) * 64 + (((4 + kq) ^ eA) * 8);

  // wave w stages groups {w, 4+w, 8+w, 12+w} for A and B (8 gl_lds per tile)
#define STAGE(buf, tk) do { \
    gl_lds16(A + aS + (size_t)(tk),              ldsA + (buf) * 8192 + w * 512); \
    gl_lds16(A + aS + 32 * (size_t)LDK + (tk),   ldsA + (buf) * 8192 + 2048 + w * 512); \
    gl_lds16(A + aS + 64 * (size_t)LDK + (tk),   ldsA + (buf) * 8192 + 4096 + w * 512); \
    gl_lds16(A + aS + 96 * (size_t)LDK + (tk),   ldsA + (buf) * 8192 + 6144 + w * 512); \
    gl_lds16(B + bS + (size_t)(tk),              ldsB + (buf) * 8192 + w * 512); \
    gl_lds16(B + bS + 32 * (size_t)LDK + (tk),   ldsB + (buf) * 8192 + 2048 + w * 512); \
    gl_lds16(B + bS + 64 * (size_t)LDK + (tk),   ldsB + (buf) * 8192 + 4096 + w * 512); \
    gl_lds16(B + bS + 96 * (size_t)LDK + (tk),   ldsB + (buf) * 8192 + 6144 + w * 512); \
  } while (0)

  const fx4 fz = {0.f, 0.f, 0.f, 0.f};
  fx4 acc[4][4];
#pragma unroll
  for (int i = 0; i < 4; ++i)
#pragma unroll
    for (int j = 0; j < 4; ++j) acc[i][j] = fz;

  bf16x8 a[4][2], b[4][2];

  // 16 reads, B-block first, then A i-pairs (in-order retire feeds the ladder).
  // byte imms: buf*16384 + i*2048 (16 rows x 128 B)
#define RD_B8_A8(buf) do { \
    b[0][0] = dsr128<(buf) * 16384 +    0>(baseB0); \
    b[1][0] = dsr128<(buf) * 16384 + 2048>(baseB0); \
    b[2][0] = dsr128<(buf) * 16384 + 4096>(baseB0); \
    b[3][0] = dsr128<(buf) * 16384 + 6144>(baseB0); \
    b[0][1] = dsr128<(buf) * 16384 +    0>(baseB1); \
    b[1][1] = dsr128<(buf) * 16384 + 2048>(baseB1); \
    b[2][1] = dsr128<(buf) * 16384 + 4096>(baseB1); \
    b[3][1] = dsr128<(buf) * 16384 + 6144>(baseB1); \
    a[0][0] = dsr128<(buf) * 16384 +    0>(baseA0); \
    a[0][1] = dsr128<(buf) * 16384 +    0>(baseA1); \
    a[1][0] = dsr128<(buf) * 16384 + 2048>(baseA0); \
    a[1][1] = dsr128<(buf) * 16384 + 2048>(baseA1); \
    a[2][0] = dsr128<(buf) * 16384 + 4096>(baseA0); \
    a[2][1] = dsr128<(buf) * 16384 + 4096>(baseA1); \
    a[3][0] = dsr128<(buf) * 16384 + 6144>(baseA0); \
    a[3][1] = dsr128<(buf) * 16384 + 6144>(baseA1); \
  } while (0)

#define MFMA_ROW(i) do { _Pragma("unroll") \
    for (int j = 0; j < 4; ++j) { \
      acc[i][j] = __builtin_amdgcn_mfma_f32_16x16x32_bf16(a[i][0], b[j][0], acc[i][j], 0, 0, 0); \
      acc[i][j] = __builtin_amdgcn_mfma_f32_16x16x32_bf16(a[i][1], b[j][1], acc[i][j], 0, 0, 0); \
    } } while (0)

#define SB0()   __builtin_amdgcn_sched_barrier(0)
#define BARS()  do { SB0(); __builtin_amdgcn_s_barrier(); SB0(); } while (0)
#define LGKM(n) do { asm volatile("s_waitcnt lgkmcnt(" #n ")" ::: "memory"); SB0(); } while (0)
#define VM8()   do { asm volatile("s_waitcnt vmcnt(8)" ::: "memory"); SB0(); } while (0)
#define VM0()   do { asm volatile("s_waitcnt vmcnt(0)" ::: "memory"); SB0(); } while (0)

  // ladder: wait 10 oldest (all B + a[0]) -> row0; +2 -> row1; +2 -> row2; all -> row3
#define LADDER(buf) do { \
    RD_B8_A8(buf); \
    __builtin_amdgcn_s_setprio(1); \
    LGKM(6); MFMA_ROW(0); \
    LGKM(4); MFMA_ROW(1); \
    LGKM(2); MFMA_ROW(2); \
    LGKM(0); MFMA_ROW(3); \
    __builtin_amdgcn_s_setprio(0); \
  } while (0)

#define HALF(buf, nbuf, tk) do { \
    STAGE(nbuf, tk); \
    VM8(); BARS(); \
    LADDER(buf); \
    BARS(); \
  } while (0)

  // prologue: tile0 -> buf0
  STAGE(0, 0);
#pragma unroll 1
  for (int t = 0; t < KT / 2 - 1; ++t) {
    HALF(0, 1, (2 * t + 1) * 64); // consume tile 2t (buf0); prefetch 2t+1 -> buf1
    HALF(1, 0, (2 * t + 2) * 64); // consume tile 2t+1 (buf1); prefetch 2t+2 -> buf0
  }
  // tile KT-2 (buf0), prefetch final tile KT-1 -> buf1
  HALF(0, 1, (KT - 1) * 64);
  // final tile KT-1 (buf1): no prefetch; drain
  VM0(); BARS();
  LADDER(1);

  // ---------------- epilogues ----------------
  const int gcol0 = n0 + wn * 64 + fr;      // true col, + j*16
  const int scol  = n0 + wn * 64 + fr * 4;  // permuted stored col base

  if constexpr (EPI == 0) {
    // proj: +bias, permuted bf16 store, row-sumsq (of ROUNDED values) atomics
#pragma unroll
    for (int i = 0; i < 4; ++i)
#pragma unroll
      for (int r = 0; r < 4; ++r) {
        const int gm = m0 + wm * 64 + i * 16 + kq * 4 + r;
        float racc = 0.f;
        ushort4 o; unsigned short* op = (unsigned short*)&o;
#pragma unroll
        for (int j = 0; j < 4; ++j) {
          float e = acc[i][j][r] + bias[gcol0 + j * 16];
          unsigned short eb = f2bf(e);
          op[j] = eb;
          float ev = bf2f(eb);
          racc += ev * ev;
        }
        *(ushort4*)(Cb + (size_t)gm * DIM + scol) = o;
        racc += __shfl_xor(racc, 1, 64);
        racc += __shfl_xor(racc, 2, 64);
        racc += __shfl_xor(racc, 4, 64);
        racc += __shfl_xor(racc, 8, 64);
        if (fr == 0) atomicAdd(&red[gm], racc);
      }
  } else if constexpr (EPI == 1) {
    // score: E = exp(-sqrt(max(sqs+sqt-2c,0))/T), permuted bf16 store, row sums
    const float invT = 1.0f / tempPtr[0];
#pragma unroll
    for (int i = 0; i < 4; ++i)
#pragma unroll
      for (int r = 0; r < 4; ++r) {
        const int gm = m0 + wm * 64 + i * 16 + kq * 4 + r;
        const float si = sqs[gm];
        float racc = 0.f;
        ushort4 o; unsigned short* op = (unsigned short*)&o;
#pragma unroll
        for (int j = 0; j < 4; ++j) {
          float d2 = si + sqt[gcol0 + j * 16] - 2.0f * acc[i][j][r];
          float c = sqrtf(fmaxf(d2, 0.0f));
          unsigned short eb = f2bf(__expf(-c * invT));
          op[j] = eb;
          racc += bf2f(eb);
        }
        *(ushort4*)(Eb + (size_t)gm * NTGT + scol) = o;
        racc += __shfl_xor(racc, 1, 64);
        racc += __shfl_xor(racc, 2, 64);
        racc += __shfl_xor(racc, 4, 64);
        racc += __shfl_xor(racc, 8, 64);
        if (fr == 0) atomicAdd(&red[gm], racc);
      }
  } else {
    // split-K PV: fp32 partials, permuted float4 stores
    float* Pz = Cf + (size_t)blockIdx.z * NSRC * DIM;
#pragma unroll
    for (int i = 0; i < 4; ++i)
#pragma unroll
      for (int r = 0; r < 4; ++r) {
        const int gm = m0 + wm * 64 + i * 16 + kq * 4 + r;
        float4 v = make_float4(acc[i][0][r], acc[i][1][r], acc[i][2][r], acc[i][3][r]);
        *(float4*)(Pz + (size_t)gm * DIM + scol) = v;
      }
  }
#undef STAGE
#undef RD_B8_A8
#undef MFMA_ROW
#undef LADDER
#undef HALF
#undef SB0
#undef BARS
#undef LGKM
#undef VM8
#undef VM0
}

// ---------------- launch ----------------
extern "C" void kernel_launch(void* const* d_in, const int* in_sizes, int n_in,
                              void* d_out, int out_size, void* d_ws, size_t ws_size,
                              hipStream_t stream) {
  const float* source = (const float*)d_in[0];
  const float* target = (const float*)d_in[1];
  const float* W_src  = (const float*)d_in[2];
  const float* b_src  = (const float*)d_in[3];
  const float* W_tgt  = (const float*)d_in[4];
  const float* b_tgt  = (const float*)d_in[5];
  const float* temp   = (const float*)d_in[6];

  float* out     = (float*)d_out;
  float* aligned = out;                         // [NSRC][DIM]
  float* Kout    = out + (size_t)NSRC * DIM;    // final K; staging for split-K partials
  float* parts   = Kout;                        // 2 x [NSRC][DIM] fp32 = 32 MB

  char* ws = (char*)d_ws;
  unsigned short* src_b  = (unsigned short*)(ws + 0);
  unsigned short* tgt_b  = (unsigned short*)(ws + 8388608);
  unsigned short* Wsrc_b = (unsigned short*)(ws + 16777216);
  unsigned short* Wtgt_b = (unsigned short*)(ws + 18874368);
  unsigned short* sp_b   = (unsigned short*)(ws + 20971520);
  unsigned short* tp_b   = (unsigned short*)(ws + 29360128);
  unsigned short* tgtT_b = (unsigned short*)(ws + 37748736);
  unsigned short* E_b    = (unsigned short*)(ws + 46137344); // 32 MB
  float* sq_s  = (float*)(ws + 79691776);                    // 16 KB
  float* sq_t  = (float*)(ws + 79708160);                    // 16 KB
  float* rsums = (float*)(ws + 79724544);                    // 16 KB

  // 0) zero sq_s, sq_t, rsums (contiguous 48 KB)
  hipMemsetAsync(sq_s, 0, 3 * NSRC * sizeof(float), stream);

  // 1) conversions + permuted target transpose
  k_convert_all<<<10240, 256, 0, stream>>>(source, target, W_src, W_tgt,
                                           src_b, tgt_b, Wsrc_b, Wtgt_b);
  k_transpose_bf16<<<dim3(DIM / 32, NTGT / 32), dim3(32, 8), 0, stream>>>(target, tgtT_b, NTGT, DIM);

  // 2) both projections (z selects problem); outputs permuted in DIM; row-sumsq fused
  k_tile128<0, DIM, 16><<<dim3(DIM / 128, NSRC / 128, 2), 256, 0, stream>>>(
      src_b, Wsrc_b, tgt_b, Wtgt_b, b_src, b_tgt, sp_b, tp_b,
      nullptr, nullptr, nullptr, nullptr, nullptr, sq_s, sq_t);

  // 3) score: E bf16 (permuted in NTGT) -> ws, row sums -> rsums
  k_tile128<1, DIM, 16><<<dim3(NTGT / 128, NSRC / 128, 1), 256, 0, stream>>>(
      sp_b, tp_b, nullptr, nullptr, nullptr, nullptr, nullptr, nullptr,
      E_b, nullptr, sq_s, sq_t, temp, rsums, nullptr);

  // 4) E @ target: split-K x2 (chunk=2048), permuted float4 partials into d_out K region
  k_tile128<3, NTGT, 32><<<dim3(DIM / 128, NSRC / 128, 2), 256, 0, stream>>>(
      E_b, tgtT_b, nullptr, nullptr, nullptr, nullptr, nullptr, nullptr,
      nullptr, parts, nullptr, nullptr, nullptr, nullptr, nullptr);

  // 5) finalize: aligned first (reads parts), then K (overwrites parts region)
  k_finalize_aligned<<<4096, 256, 0, stream>>>(parts, aligned, rsums);
  k_finalize_K<<<8192, 256, 0, stream>>>(E_b, Kout, rsums);
}